// Round 10
// baseline (182.802 us; speedup 1.0000x reference)
//
#include <hip/hip_runtime.h>

typedef short bf16x8_t __attribute__((ext_vector_type(8)));
typedef float f32x4_t __attribute__((ext_vector_type(4)));

__device__ __forceinline__ float bf2f(unsigned short h) {
  union { unsigned int u; float f; } v; v.u = ((unsigned int)h) << 16; return v.f;
}
__device__ __forceinline__ unsigned short f2bf(float f) {
  union { float f; unsigned int u; } v; v.f = f;
  unsigned int u = v.u + 0x7FFFu + ((v.u >> 16) & 1u);
  return (unsigned short)(u >> 16);
}
__device__ __forceinline__ unsigned int fbits(float f) {
  return __builtin_bit_cast(unsigned int, f);
}
// 2^x via v_exp_f32 directly (NOT __exp2f: glibc math.h macroizes that name
// on this toolchain and breaks the build -- round 9).
__device__ __forceinline__ float exp2_hw(float x) {
  return __builtin_amdgcn_exp2f(x);
}

// Static device workspace. Inputs/outputs are f32 (confirmed round 3).
__device__ __align__(16) unsigned short g_hT[16 * 1024 * 256];     // GN out [b][n][c]; reused as attn OT
__device__ __align__(16) unsigned short g_qT[16 * 4 * 1024 * 64];  // [b][h][n][d]
__device__ __align__(16) unsigned short g_kT[16 * 4 * 1024 * 64];  // [b][h][n][d]
__device__ __align__(16) unsigned short g_vN[16 * 4 * 64 * 1024];  // [b][h][d][n]

__device__ __forceinline__ uint4 pack8(const float4* src) {
  float4 a = src[0], b = src[1];
  union { unsigned short u[8]; uint4 v; } r;
  r.u[0] = f2bf(a.x); r.u[1] = f2bf(a.y); r.u[2] = f2bf(a.z); r.u[3] = f2bf(a.w);
  r.u[4] = f2bf(b.x); r.u[5] = f2bf(b.y); r.u[6] = f2bf(b.z); r.u[7] = f2bf(b.w);
  return r.v;
}

// ---------------------------------------------------------------------------
// Kernel 1: GroupNorm.  x[b][c][n] f32 -> g_hT[b][n][c] bf16 (transposed)
// ---------------------------------------------------------------------------
__global__ __launch_bounds__(256) void gn_kernel(
    const float* __restrict__ x, const float* __restrict__ gamma,
    const float* __restrict__ beta) {
  const int b = blockIdx.x >> 5, g = blockIdx.x & 31;
  const int t = threadIdx.x;
  const float4* xg = (const float4*)(x + (size_t)(b * 256 + g * 8) * 1024);

  __shared__ __align__(16) unsigned short lds[8192];
  __shared__ float red[16];

  float vals[32];
  float s = 0.f, sq = 0.f;
#pragma unroll
  for (int p = 0; p < 4; ++p) {
    int idx = t + p * 256;
    float4 a = xg[2 * idx], c = xg[2 * idx + 1];
    float tmp[8] = {a.x, a.y, a.z, a.w, c.x, c.y, c.z, c.w};
#pragma unroll
    for (int j = 0; j < 8; ++j) {
      vals[p * 8 + j] = tmp[j];
      s += tmp[j]; sq += tmp[j] * tmp[j];
    }
  }
#pragma unroll
  for (int m = 32; m; m >>= 1) {
    s += __shfl_xor(s, m, 64);
    sq += __shfl_xor(sq, m, 64);
  }
  const int w = t >> 6;
  if ((t & 63) == 0) { red[w] = s; red[8 + w] = sq; }
  __syncthreads();
  s = red[0] + red[1] + red[2] + red[3];
  sq = red[8] + red[9] + red[10] + red[11];
  const float mu = s * (1.f / 8192.f);
  const float var = sq * (1.f / 8192.f) - mu * mu;
  const float rstd = rsqrtf(var + 1e-5f);

#pragma unroll
  for (int p = 0; p < 4; ++p) {
    int idx = t + p * 256;
    int c = idx >> 7;
    float ga = gamma[g * 8 + c] * rstd;
    float be = beta[g * 8 + c] - mu * ga;
    union { unsigned short u[8]; uint4 v; } pk;
#pragma unroll
    for (int j = 0; j < 8; ++j) pk.u[j] = f2bf(vals[p * 8 + j] * ga + be);
    ((uint4*)lds)[idx] = pk.v;
  }
  __syncthreads();

  unsigned short* dstbase = g_hT + (size_t)b * 1024 * 256 + g * 8;
#pragma unroll
  for (int p = 0; p < 4; ++p) {
    int n = t + p * 256;
    union { unsigned short u[8]; uint4 v; } pk;
#pragma unroll
    for (int c = 0; c < 8; ++c) pk.u[c] = lds[c * 1024 + n];
    *(uint4*)(dstbase + (size_t)n * 256) = pk.v;
  }
}

// ---------------------------------------------------------------------------
// Kernel 2: channel GEMM  C[o][n] = sum_k W[o][k] * hT[n][k]  (K = 256)
// 64 (o) x 256 (n) tile, BK=64, 4 K-iters, round-5 grid (x=n, y=oty, z=b),
// padded staging (65/257). Register prefetch of tile kb+1 issued right
// after the stage-barrier (de-confounded retest of round-6's prefetch).
// ---------------------------------------------------------------------------
template <int MODE>
__global__ __launch_bounds__(256) void gemm_ct(
    const float* __restrict__ W, const float* __restrict__ bias,
    const float* __restrict__ xres, float* __restrict__ outp) {
  const int n0 = blockIdx.x * 256;
  const int oty = blockIdx.y, o0 = oty * 64;
  const int b = blockIdx.z;
  const int t = threadIdx.x;
  const int w = t >> 6, lane = t & 63, quad = lane >> 4, l15 = lane & 15;
  const int kcA = t & 7, rowA = t >> 3;

  __shared__ uint4 as[8 * 65];    // [kc][row] stride 65
  __shared__ uint4 bs[8 * 257];   // [kc][row] stride 257

  const uint4* Bv = (const uint4*)g_hT;

  f32x4_t acc[4][4];
#pragma unroll
  for (int i = 0; i < 4; ++i)
#pragma unroll
    for (int j = 0; j < 4; ++j) acc[i][j] = (f32x4_t){0.f, 0.f, 0.f, 0.f};

  // prefetch tile kb=0 into registers
  float4 a0[2], a1[2];
  uint4 brg[8];
#pragma unroll
  for (int p = 0; p < 2; ++p) {
    const float4* src = (const float4*)(W + (size_t)(o0 + rowA + p * 32) * 256) + kcA * 2;
    a0[p] = src[0]; a1[p] = src[1];
  }
#pragma unroll
  for (int p = 0; p < 8; ++p)
    brg[p] = Bv[(size_t)(b * 1024 + n0 + rowA + p * 32) * 32 + kcA];

  for (int kb = 0; kb < 4; ++kb) {
#pragma unroll
    for (int p = 0; p < 2; ++p) {
      union { unsigned short u[8]; uint4 v; } pk;
      float tmp[8] = {a0[p].x, a0[p].y, a0[p].z, a0[p].w, a1[p].x, a1[p].y, a1[p].z, a1[p].w};
#pragma unroll
      for (int j = 0; j < 8; ++j) pk.u[j] = f2bf(tmp[j]);
      as[kcA * 65 + rowA + p * 32] = pk.v;
    }
#pragma unroll
    for (int p = 0; p < 8; ++p)
      bs[kcA * 257 + rowA + p * 32] = brg[p];
    __syncthreads();

    if (kb < 3) {  // issue next tile's loads; consumed next iteration
#pragma unroll
      for (int p = 0; p < 2; ++p) {
        const float4* src = (const float4*)(W + (size_t)(o0 + rowA + p * 32) * 256 + (kb + 1) * 64) + kcA * 2;
        a0[p] = src[0]; a1[p] = src[1];
      }
#pragma unroll
      for (int p = 0; p < 8; ++p)
        brg[p] = Bv[(size_t)(b * 1024 + n0 + rowA + p * 32) * 32 + (kb + 1) * 8 + kcA];
    }

#pragma unroll
    for (int kk = 0; kk < 2; ++kk) {
      int ch = kk * 4 + quad;
      bf16x8_t af[4];
#pragma unroll
      for (int i = 0; i < 4; ++i)
        af[i] = __builtin_bit_cast(bf16x8_t, as[ch * 65 + i * 16 + l15]);
#pragma unroll
      for (int j = 0; j < 4; ++j) {
        bf16x8_t bf = __builtin_bit_cast(bf16x8_t, bs[ch * 257 + w * 64 + j * 16 + l15]);
#pragma unroll
        for (int i = 0; i < 4; ++i)
          acc[i][j] = __builtin_amdgcn_mfma_f32_16x16x32_bf16(af[i], bf, acc[i][j], 0, 0, 0);
      }
    }
    __syncthreads();
  }

  float bi[4][4];
#pragma unroll
  for (int i = 0; i < 4; ++i)
#pragma unroll
    for (int r = 0; r < 4; ++r) bi[i][r] = bias[o0 + i * 16 + quad * 4 + r];

  if (MODE == 0) {
    const int head = oty / 3, type = oty % 3;
    if (type < 2) {
      unsigned short* dst = (type == 0 ? g_qT : g_kT) + (size_t)(b * 4 + head) * 65536;
#pragma unroll
      for (int j = 0; j < 4; ++j) {
        int n = n0 + w * 64 + j * 16 + l15;
#pragma unroll
        for (int i = 0; i < 4; ++i) {
          ushort4 pk;
          pk.x = f2bf(acc[i][j][0] + bi[i][0]);
          pk.y = f2bf(acc[i][j][1] + bi[i][1]);
          pk.z = f2bf(acc[i][j][2] + bi[i][2]);
          pk.w = f2bf(acc[i][j][3] + bi[i][3]);
          *(ushort4*)(dst + (size_t)n * 64 + i * 16 + quad * 4) = pk;
        }
      }
    } else {
      unsigned short* dst = g_vN + (size_t)(b * 4 + head) * 65536;
#pragma unroll
      for (int j = 0; j < 4; ++j) {
        int n = n0 + w * 64 + j * 16 + l15;
#pragma unroll
        for (int i = 0; i < 4; ++i)
#pragma unroll
          for (int r = 0; r < 4; ++r)
            dst[(size_t)(i * 16 + quad * 4 + r) * 1024 + n] = f2bf(acc[i][j][r] + bi[i][r]);
      }
    }
  } else {
#pragma unroll
    for (int i = 0; i < 4; ++i)
#pragma unroll
      for (int r = 0; r < 4; ++r) {
        int c = o0 + i * 16 + quad * 4 + r;
        const float* xr = xres + (((size_t)b * 256 + c) << 10);
        float* op = outp + (((size_t)b * 256 + c) << 10);
#pragma unroll
        for (int j = 0; j < 4; ++j) {
          int n = n0 + w * 64 + j * 16 + l15;
          op[n] = acc[i][j][r] + bi[i][r] + xr[n];
        }
      }
  }
}

// ---------------------------------------------------------------------------
// Kernel 3: flash attention, transposed-P, two q-tiles per block (round-8).
// Softmax VALU diet: p = exp2_hw(s * 0.125*log2e) (one mul + v_exp_f32) and
// P packed by TRUNCATION pairs ((u0>>16)|(u1&0xFFFF0000)) instead of 4-op
// RNE f2bf. Truncation biases P down <=0.4%; output error ~0.2% << 2%
// threshold. rsum keeps full-precision p.
// ---------------------------------------------------------------------------
__global__ __launch_bounds__(256) void attn_kernel() {
  const int bh = blockIdx.x;
  const int n0 = blockIdx.y * 128;
  const int t = threadIdx.x;
  const int w = t >> 6, lane = t & 63, quad = lane >> 4, l15 = lane & 15;
  const int b = bh >> 2, h = bh & 3;

  const uint4* qv = (const uint4*)(g_qT + (size_t)bh * 65536);
  const uint4* kv = (const uint4*)(g_kT + (size_t)bh * 65536);
  const uint4* vv = (const uint4*)(g_vN + (size_t)bh * 65536);

  __shared__ uint4 ks[2][512];  // [chunk][row^chunk]  XOR-swizzled
  __shared__ uint4 vs[2][512];
  __shared__ __align__(16) unsigned short Pt[2 * 4 * 16 * 72];  // [tile][wave][qrow][m']

  uint4 qrA[2], qrB[2];
#pragma unroll
  for (int kk = 0; kk < 2; ++kk) {
    qrA[kk] = qv[(size_t)(n0 + w * 16 + l15) * 8 + kk * 4 + quad];
    qrB[kk] = qv[(size_t)(n0 + 64 + w * 16 + l15) * 8 + kk * 4 + quad];
  }

  const int rr0 = t >> 3, cc = t & 7, rr1 = rr0 + 32;
  uint4 kr0 = kv[rr0 * 8 + cc], kr1 = kv[rr1 * 8 + cc];
  uint4 vr0 = vv[rr0 * 128 + cc], vr1 = vv[rr1 * 128 + cc];

  f32x4_t OA[4], OB[4];
#pragma unroll
  for (int i = 0; i < 4; ++i) {
    OA[i] = (f32x4_t){0.f, 0.f, 0.f, 0.f};
    OB[i] = (f32x4_t){0.f, 0.f, 0.f, 0.f};
  }
  float rsumA = 0.f, rsumB = 0.f;

  unsigned short* PwA = Pt + w * 1152;
  unsigned short* PwB = Pt + 4608 + w * 1152;
  const float C = 0.18033688f;  // 0.125 * log2(e)

#pragma unroll 1
  for (int mt = 0; mt < 16; ++mt) {
    uint4* kb = ks[mt & 1];
    uint4* vb = vs[mt & 1];
    kb[cc * 64 + (rr0 ^ cc)] = kr0; kb[cc * 64 + (rr1 ^ cc)] = kr1;
    vb[cc * 64 + (rr0 ^ cc)] = vr0; vb[cc * 64 + (rr1 ^ cc)] = vr1;
    __syncthreads();  // the ONLY barrier per iteration

    if (mt < 15) {
      int m1 = (mt + 1) * 64;
      kr0 = kv[(m1 + rr0) * 8 + cc]; kr1 = kv[(m1 + rr1) * 8 + cc];
      vr0 = vv[rr0 * 128 + (mt + 1) * 8 + cc]; vr1 = vv[rr1 * 128 + (mt + 1) * 8 + cc];
    }

    f32x4_t sA[4], sB[4];
#pragma unroll
    for (int i = 0; i < 4; ++i) {
      sA[i] = (f32x4_t){0.f, 0.f, 0.f, 0.f};
      sB[i] = (f32x4_t){0.f, 0.f, 0.f, 0.f};
    }
#pragma unroll
    for (int kk = 0; kk < 2; ++kk) {
      int ch = kk * 4 + quad;
      bf16x8_t bqA = __builtin_bit_cast(bf16x8_t, qrA[kk]);
      bf16x8_t bqB = __builtin_bit_cast(bf16x8_t, qrB[kk]);
#pragma unroll
      for (int ms = 0; ms < 4; ++ms) {
        bf16x8_t ak = __builtin_bit_cast(bf16x8_t, kb[ch * 64 + ((ms * 16 + l15) ^ ch)]);
        sA[ms] = __builtin_amdgcn_mfma_f32_16x16x32_bf16(ak, bqA, sA[ms], 0, 0, 0);
        sB[ms] = __builtin_amdgcn_mfma_f32_16x16x32_bf16(ak, bqB, sB[ms], 0, 0, 0);
      }
    }

    // p = exp2(s*C); truncation-pack pairs; full-precision row sums
#pragma unroll
    for (int ms = 0; ms < 4; ++ms) {
      float a0 = exp2_hw(sA[ms][0] * C), a1 = exp2_hw(sA[ms][1] * C);
      float a2 = exp2_hw(sA[ms][2] * C), a3 = exp2_hw(sA[ms][3] * C);
      float b0 = exp2_hw(sB[ms][0] * C), b1 = exp2_hw(sB[ms][1] * C);
      float b2 = exp2_hw(sB[ms][2] * C), b3 = exp2_hw(sB[ms][3] * C);
      rsumA += (a0 + a1) + (a2 + a3);
      rsumB += (b0 + b1) + (b2 + b3);
      uint2 pA, pB;
      pA.x = (fbits(a0) >> 16) | (fbits(a1) & 0xFFFF0000u);
      pA.y = (fbits(a2) >> 16) | (fbits(a3) & 0xFFFF0000u);
      pB.x = (fbits(b0) >> 16) | (fbits(b1) & 0xFFFF0000u);
      pB.y = (fbits(b2) >> 16) | (fbits(b3) & 0xFFFF0000u);
      *(uint2*)(PwA + l15 * 72 + ms * 16 + quad * 4) = pA;
      *(uint2*)(PwB + l15 * 72 + ms * 16 + quad * 4) = pB;
    }

#pragma unroll
    for (int km = 0; km < 2; ++km) {
      int ch = km * 4 + quad;
      bf16x8_t bpA = *(const bf16x8_t*)(PwA + l15 * 72 + km * 32 + quad * 8);
      bf16x8_t bpB = *(const bf16x8_t*)(PwB + l15 * 72 + km * 32 + quad * 8);
#pragma unroll
      for (int ds = 0; ds < 4; ++ds) {
        bf16x8_t av = __builtin_bit_cast(bf16x8_t, vb[ch * 64 + ((ds * 16 + l15) ^ ch)]);
        OA[ds] = __builtin_amdgcn_mfma_f32_16x16x32_bf16(av, bpA, OA[ds], 0, 0, 0);
        OB[ds] = __builtin_amdgcn_mfma_f32_16x16x32_bf16(av, bpB, OB[ds], 0, 0, 0);
      }
    }
  }

  rsumA += __shfl_xor(rsumA, 16, 64);
  rsumA += __shfl_xor(rsumA, 32, 64);
  rsumB += __shfl_xor(rsumB, 16, 64);
  rsumB += __shfl_xor(rsumB, 32, 64);
  const float invA = 1.f / rsumA, invB = 1.f / rsumB;

  unsigned short* dstA = g_hT + ((size_t)b * 1024 + n0 + w * 16 + l15) * 256 + h * 64;
  unsigned short* dstB = dstA + (size_t)64 * 256;
#pragma unroll
  for (int ds = 0; ds < 4; ++ds) {
    ushort4 pkA, pkB;
    pkA.x = f2bf(OA[ds][0] * invA); pkA.y = f2bf(OA[ds][1] * invA);
    pkA.z = f2bf(OA[ds][2] * invA); pkA.w = f2bf(OA[ds][3] * invA);
    pkB.x = f2bf(OB[ds][0] * invB); pkB.y = f2bf(OB[ds][1] * invB);
    pkB.z = f2bf(OB[ds][2] * invB); pkB.w = f2bf(OB[ds][3] * invB);
    *(ushort4*)(dstA + ds * 16 + quad * 4) = pkA;
    *(ushort4*)(dstB + ds * 16 + quad * 4) = pkB;
  }
}

// ---------------------------------------------------------------------------
extern "C" void kernel_launch(void* const* d_in, const int* in_sizes, int n_in,
                              void* d_out, int out_size, void* d_ws, size_t ws_size,
                              hipStream_t stream) {
  const float* x = (const float*)d_in[0];
  const float* gam = (const float*)d_in[1];
  const float* bet = (const float*)d_in[2];
  const float* qkv_w = (const float*)d_in[3];
  const float* qkv_b = (const float*)d_in[4];
  const float* pr_w = (const float*)d_in[5];
  const float* pr_b = (const float*)d_in[6];
  float* out = (float*)d_out;

  gn_kernel<<<512, 256, 0, stream>>>(x, gam, bet);
  gemm_ct<0><<<dim3(4, 12, 16), 256, 0, stream>>>(qkv_w, qkv_b, nullptr, nullptr);
  attn_kernel<<<dim3(64, 8), 256, 0, stream>>>();
  gemm_ct<1><<<dim3(4, 4, 16), 256, 0, stream>>>(pr_w, pr_b, x, out);
}

// Round 11
// 146.209 us; speedup vs baseline: 1.2503x; 1.2503x over previous
//
#include <hip/hip_runtime.h>

typedef short bf16x8_t __attribute__((ext_vector_type(8)));
typedef float f32x4_t __attribute__((ext_vector_type(4)));

__device__ __forceinline__ float bf2f(unsigned short h) {
  union { unsigned int u; float f; } v; v.u = ((unsigned int)h) << 16; return v.f;
}
__device__ __forceinline__ unsigned short f2bf(float f) {
  union { float f; unsigned int u; } v; v.f = f;
  unsigned int u = v.u + 0x7FFFu + ((v.u >> 16) & 1u);
  return (unsigned short)(u >> 16);
}
__device__ __forceinline__ unsigned int fbits(float f) {
  return __builtin_bit_cast(unsigned int, f);
}
// 2^x via v_exp_f32 directly (NOT __exp2f: glibc math.h macroizes that name
// on this toolchain and breaks the build -- round 9).
__device__ __forceinline__ float exp2_hw(float x) {
  return __builtin_amdgcn_exp2f(x);
}

// Static device workspace. Inputs/outputs are f32 (confirmed round 3).
__device__ __align__(16) unsigned short g_hT[16 * 1024 * 256];     // GN out [b][n][c]; reused as attn OT
__device__ __align__(16) unsigned short g_qT[16 * 4 * 1024 * 64];  // [b][h][n][d]
__device__ __align__(16) unsigned short g_kT[16 * 4 * 1024 * 64];  // [b][h][n][d]
__device__ __align__(16) unsigned short g_vN[16 * 4 * 64 * 1024];  // [b][h][d][n]

__device__ __forceinline__ uint4 pack8(const float4* src) {
  float4 a = src[0], b = src[1];
  union { unsigned short u[8]; uint4 v; } r;
  r.u[0] = f2bf(a.x); r.u[1] = f2bf(a.y); r.u[2] = f2bf(a.z); r.u[3] = f2bf(a.w);
  r.u[4] = f2bf(b.x); r.u[5] = f2bf(b.y); r.u[6] = f2bf(b.z); r.u[7] = f2bf(b.w);
  return r.v;
}

// ---------------------------------------------------------------------------
// Kernel 1: GroupNorm.  x[b][c][n] f32 -> g_hT[b][n][c] bf16 (transposed)
// ---------------------------------------------------------------------------
__global__ __launch_bounds__(256) void gn_kernel(
    const float* __restrict__ x, const float* __restrict__ gamma,
    const float* __restrict__ beta) {
  const int b = blockIdx.x >> 5, g = blockIdx.x & 31;
  const int t = threadIdx.x;
  const float4* xg = (const float4*)(x + (size_t)(b * 256 + g * 8) * 1024);

  __shared__ __align__(16) unsigned short lds[8192];
  __shared__ float red[16];

  float vals[32];
  float s = 0.f, sq = 0.f;
#pragma unroll
  for (int p = 0; p < 4; ++p) {
    int idx = t + p * 256;
    float4 a = xg[2 * idx], c = xg[2 * idx + 1];
    float tmp[8] = {a.x, a.y, a.z, a.w, c.x, c.y, c.z, c.w};
#pragma unroll
    for (int j = 0; j < 8; ++j) {
      vals[p * 8 + j] = tmp[j];
      s += tmp[j]; sq += tmp[j] * tmp[j];
    }
  }
#pragma unroll
  for (int m = 32; m; m >>= 1) {
    s += __shfl_xor(s, m, 64);
    sq += __shfl_xor(sq, m, 64);
  }
  const int w = t >> 6;
  if ((t & 63) == 0) { red[w] = s; red[8 + w] = sq; }
  __syncthreads();
  s = red[0] + red[1] + red[2] + red[3];
  sq = red[8] + red[9] + red[10] + red[11];
  const float mu = s * (1.f / 8192.f);
  const float var = sq * (1.f / 8192.f) - mu * mu;
  const float rstd = rsqrtf(var + 1e-5f);

#pragma unroll
  for (int p = 0; p < 4; ++p) {
    int idx = t + p * 256;
    int c = idx >> 7;
    float ga = gamma[g * 8 + c] * rstd;
    float be = beta[g * 8 + c] - mu * ga;
    union { unsigned short u[8]; uint4 v; } pk;
#pragma unroll
    for (int j = 0; j < 8; ++j) pk.u[j] = f2bf(vals[p * 8 + j] * ga + be);
    ((uint4*)lds)[idx] = pk.v;
  }
  __syncthreads();

  unsigned short* dstbase = g_hT + (size_t)b * 1024 * 256 + g * 8;
#pragma unroll
  for (int p = 0; p < 4; ++p) {
    int n = t + p * 256;
    union { unsigned short u[8]; uint4 v; } pk;
#pragma unroll
    for (int c = 0; c < 8; ++c) pk.u[c] = lds[c * 1024 + n];
    *(uint4*)(dstbase + (size_t)n * 256) = pk.v;
  }
}

// ---------------------------------------------------------------------------
// Kernel 2: channel GEMM  C[o][n] = sum_k W[o][k] * hT[n][k]  (K = 256)
// 64 (o) x 256 (n) tile, BK=64, 4 K-iters, grid (x=n, y=oty, z=b), padded
// staging (65/257).  NO register prefetch: holding 48 prefetch VGPRs live
// across the barrier spills to scratch (r6/r10: WRITE_SIZE 92-94 MB = spill
// traffic, gemm 51-65 us).  Barrier-staged loop + ~4 blocks/CU overlap wins.
// ---------------------------------------------------------------------------
template <int MODE>
__global__ __launch_bounds__(256) void gemm_ct(
    const float* __restrict__ W, const float* __restrict__ bias,
    const float* __restrict__ xres, float* __restrict__ outp) {
  const int n0 = blockIdx.x * 256;
  const int oty = blockIdx.y, o0 = oty * 64;
  const int b = blockIdx.z;
  const int t = threadIdx.x;
  const int w = t >> 6, lane = t & 63, quad = lane >> 4, l15 = lane & 15;
  const int kcA = t & 7, rowA = t >> 3;

  __shared__ uint4 as[8 * 65];    // [kc][row] stride 65
  __shared__ uint4 bs[8 * 257];   // [kc][row] stride 257

  const uint4* Bv = (const uint4*)g_hT;

  f32x4_t acc[4][4];
#pragma unroll
  for (int i = 0; i < 4; ++i)
#pragma unroll
    for (int j = 0; j < 4; ++j) acc[i][j] = (f32x4_t){0.f, 0.f, 0.f, 0.f};

  for (int kb = 0; kb < 4; ++kb) {
#pragma unroll
    for (int p = 0; p < 2; ++p) {
      int row = rowA + p * 32;
      as[kcA * 65 + row] = pack8((const float4*)(W + (size_t)(o0 + row) * 256 + kb * 64) + kcA * 2);
    }
#pragma unroll
    for (int p = 0; p < 8; ++p) {
      int row = rowA + p * 32;
      bs[kcA * 257 + row] = Bv[(size_t)(b * 1024 + n0 + row) * 32 + kb * 8 + kcA];
    }
    __syncthreads();
#pragma unroll
    for (int kk = 0; kk < 2; ++kk) {
      int ch = kk * 4 + quad;
      bf16x8_t af[4];
#pragma unroll
      for (int i = 0; i < 4; ++i)
        af[i] = __builtin_bit_cast(bf16x8_t, as[ch * 65 + i * 16 + l15]);
#pragma unroll
      for (int j = 0; j < 4; ++j) {
        bf16x8_t bf = __builtin_bit_cast(bf16x8_t, bs[ch * 257 + w * 64 + j * 16 + l15]);
#pragma unroll
        for (int i = 0; i < 4; ++i)
          acc[i][j] = __builtin_amdgcn_mfma_f32_16x16x32_bf16(af[i], bf, acc[i][j], 0, 0, 0);
      }
    }
    __syncthreads();
  }

  float bi[4][4];
#pragma unroll
  for (int i = 0; i < 4; ++i)
#pragma unroll
    for (int r = 0; r < 4; ++r) bi[i][r] = bias[o0 + i * 16 + quad * 4 + r];

  if (MODE == 0) {
    const int head = oty / 3, type = oty % 3;
    if (type < 2) {
      unsigned short* dst = (type == 0 ? g_qT : g_kT) + (size_t)(b * 4 + head) * 65536;
#pragma unroll
      for (int j = 0; j < 4; ++j) {
        int n = n0 + w * 64 + j * 16 + l15;
#pragma unroll
        for (int i = 0; i < 4; ++i) {
          ushort4 pk;
          pk.x = f2bf(acc[i][j][0] + bi[i][0]);
          pk.y = f2bf(acc[i][j][1] + bi[i][1]);
          pk.z = f2bf(acc[i][j][2] + bi[i][2]);
          pk.w = f2bf(acc[i][j][3] + bi[i][3]);
          *(ushort4*)(dst + (size_t)n * 64 + i * 16 + quad * 4) = pk;
        }
      }
    } else {
      unsigned short* dst = g_vN + (size_t)(b * 4 + head) * 65536;
#pragma unroll
      for (int j = 0; j < 4; ++j) {
        int n = n0 + w * 64 + j * 16 + l15;
#pragma unroll
        for (int i = 0; i < 4; ++i)
#pragma unroll
          for (int r = 0; r < 4; ++r)
            dst[(size_t)(i * 16 + quad * 4 + r) * 1024 + n] = f2bf(acc[i][j][r] + bi[i][r]);
      }
    }
  } else {
#pragma unroll
    for (int i = 0; i < 4; ++i)
#pragma unroll
      for (int r = 0; r < 4; ++r) {
        int c = o0 + i * 16 + quad * 4 + r;
        const float* xr = xres + (((size_t)b * 256 + c) << 10);
        float* op = outp + (((size_t)b * 256 + c) << 10);
#pragma unroll
        for (int j = 0; j < 4; ++j) {
          int n = n0 + w * 64 + j * 16 + l15;
          op[n] = acc[i][j][r] + bi[i][r] + xr[n];
        }
      }
  }
}

// ---------------------------------------------------------------------------
// Kernel 3: flash attention, transposed-P, two q-tiles per block (round-8)
// + softmax VALU diet (round-10, kept): p = exp2_hw(s * 0.125*log2e) and
// P packed by truncation pairs. absmax 0.03125 << 0.1006 threshold.
// ---------------------------------------------------------------------------
__global__ __launch_bounds__(256) void attn_kernel() {
  const int bh = blockIdx.x;
  const int n0 = blockIdx.y * 128;
  const int t = threadIdx.x;
  const int w = t >> 6, lane = t & 63, quad = lane >> 4, l15 = lane & 15;
  const int b = bh >> 2, h = bh & 3;

  const uint4* qv = (const uint4*)(g_qT + (size_t)bh * 65536);
  const uint4* kv = (const uint4*)(g_kT + (size_t)bh * 65536);
  const uint4* vv = (const uint4*)(g_vN + (size_t)bh * 65536);

  __shared__ uint4 ks[2][512];  // [chunk][row^chunk]  XOR-swizzled
  __shared__ uint4 vs[2][512];
  __shared__ __align__(16) unsigned short Pt[2 * 4 * 16 * 72];  // [tile][wave][qrow][m']

  uint4 qrA[2], qrB[2];
#pragma unroll
  for (int kk = 0; kk < 2; ++kk) {
    qrA[kk] = qv[(size_t)(n0 + w * 16 + l15) * 8 + kk * 4 + quad];
    qrB[kk] = qv[(size_t)(n0 + 64 + w * 16 + l15) * 8 + kk * 4 + quad];
  }

  const int rr0 = t >> 3, cc = t & 7, rr1 = rr0 + 32;
  uint4 kr0 = kv[rr0 * 8 + cc], kr1 = kv[rr1 * 8 + cc];
  uint4 vr0 = vv[rr0 * 128 + cc], vr1 = vv[rr1 * 128 + cc];

  f32x4_t OA[4], OB[4];
#pragma unroll
  for (int i = 0; i < 4; ++i) {
    OA[i] = (f32x4_t){0.f, 0.f, 0.f, 0.f};
    OB[i] = (f32x4_t){0.f, 0.f, 0.f, 0.f};
  }
  float rsumA = 0.f, rsumB = 0.f;

  unsigned short* PwA = Pt + w * 1152;
  unsigned short* PwB = Pt + 4608 + w * 1152;
  const float C = 0.18033688f;  // 0.125 * log2(e)

#pragma unroll 1
  for (int mt = 0; mt < 16; ++mt) {
    uint4* kb = ks[mt & 1];
    uint4* vb = vs[mt & 1];
    kb[cc * 64 + (rr0 ^ cc)] = kr0; kb[cc * 64 + (rr1 ^ cc)] = kr1;
    vb[cc * 64 + (rr0 ^ cc)] = vr0; vb[cc * 64 + (rr1 ^ cc)] = vr1;
    __syncthreads();  // the ONLY barrier per iteration

    if (mt < 15) {
      int m1 = (mt + 1) * 64;
      kr0 = kv[(m1 + rr0) * 8 + cc]; kr1 = kv[(m1 + rr1) * 8 + cc];
      vr0 = vv[rr0 * 128 + (mt + 1) * 8 + cc]; vr1 = vv[rr1 * 128 + (mt + 1) * 8 + cc];
    }

    f32x4_t sA[4], sB[4];
#pragma unroll
    for (int i = 0; i < 4; ++i) {
      sA[i] = (f32x4_t){0.f, 0.f, 0.f, 0.f};
      sB[i] = (f32x4_t){0.f, 0.f, 0.f, 0.f};
    }
#pragma unroll
    for (int kk = 0; kk < 2; ++kk) {
      int ch = kk * 4 + quad;
      bf16x8_t bqA = __builtin_bit_cast(bf16x8_t, qrA[kk]);
      bf16x8_t bqB = __builtin_bit_cast(bf16x8_t, qrB[kk]);
#pragma unroll
      for (int ms = 0; ms < 4; ++ms) {
        bf16x8_t ak = __builtin_bit_cast(bf16x8_t, kb[ch * 64 + ((ms * 16 + l15) ^ ch)]);
        sA[ms] = __builtin_amdgcn_mfma_f32_16x16x32_bf16(ak, bqA, sA[ms], 0, 0, 0);
        sB[ms] = __builtin_amdgcn_mfma_f32_16x16x32_bf16(ak, bqB, sB[ms], 0, 0, 0);
      }
    }

    // p = exp2(s*C); truncation-pack pairs; full-precision row sums
#pragma unroll
    for (int ms = 0; ms < 4; ++ms) {
      float a0 = exp2_hw(sA[ms][0] * C), a1 = exp2_hw(sA[ms][1] * C);
      float a2 = exp2_hw(sA[ms][2] * C), a3 = exp2_hw(sA[ms][3] * C);
      float b0 = exp2_hw(sB[ms][0] * C), b1 = exp2_hw(sB[ms][1] * C);
      float b2 = exp2_hw(sB[ms][2] * C), b3 = exp2_hw(sB[ms][3] * C);
      rsumA += (a0 + a1) + (a2 + a3);
      rsumB += (b0 + b1) + (b2 + b3);
      uint2 pA, pB;
      pA.x = (fbits(a0) >> 16) | (fbits(a1) & 0xFFFF0000u);
      pA.y = (fbits(a2) >> 16) | (fbits(a3) & 0xFFFF0000u);
      pB.x = (fbits(b0) >> 16) | (fbits(b1) & 0xFFFF0000u);
      pB.y = (fbits(b2) >> 16) | (fbits(b3) & 0xFFFF0000u);
      *(uint2*)(PwA + l15 * 72 + ms * 16 + quad * 4) = pA;
      *(uint2*)(PwB + l15 * 72 + ms * 16 + quad * 4) = pB;
    }

#pragma unroll
    for (int km = 0; km < 2; ++km) {
      int ch = km * 4 + quad;
      bf16x8_t bpA = *(const bf16x8_t*)(PwA + l15 * 72 + km * 32 + quad * 8);
      bf16x8_t bpB = *(const bf16x8_t*)(PwB + l15 * 72 + km * 32 + quad * 8);
#pragma unroll
      for (int ds = 0; ds < 4; ++ds) {
        bf16x8_t av = __builtin_bit_cast(bf16x8_t, vb[ch * 64 + ((ds * 16 + l15) ^ ch)]);
        OA[ds] = __builtin_amdgcn_mfma_f32_16x16x32_bf16(av, bpA, OA[ds], 0, 0, 0);
        OB[ds] = __builtin_amdgcn_mfma_f32_16x16x32_bf16(av, bpB, OB[ds], 0, 0, 0);
      }
    }
  }

  rsumA += __shfl_xor(rsumA, 16, 64);
  rsumA += __shfl_xor(rsumA, 32, 64);
  rsumB += __shfl_xor(rsumB, 16, 64);
  rsumB += __shfl_xor(rsumB, 32, 64);
  const float invA = 1.f / rsumA, invB = 1.f / rsumB;

  unsigned short* dstA = g_hT + ((size_t)b * 1024 + n0 + w * 16 + l15) * 256 + h * 64;
  unsigned short* dstB = dstA + (size_t)64 * 256;
#pragma unroll
  for (int ds = 0; ds < 4; ++ds) {
    ushort4 pkA, pkB;
    pkA.x = f2bf(OA[ds][0] * invA); pkA.y = f2bf(OA[ds][1] * invA);
    pkA.z = f2bf(OA[ds][2] * invA); pkA.w = f2bf(OA[ds][3] * invA);
    pkB.x = f2bf(OB[ds][0] * invB); pkB.y = f2bf(OB[ds][1] * invB);
    pkB.z = f2bf(OB[ds][2] * invB); pkB.w = f2bf(OB[ds][3] * invB);
    *(ushort4*)(dstA + ds * 16 + quad * 4) = pkA;
    *(ushort4*)(dstB + ds * 16 + quad * 4) = pkB;
  }
}

// ---------------------------------------------------------------------------
extern "C" void kernel_launch(void* const* d_in, const int* in_sizes, int n_in,
                              void* d_out, int out_size, void* d_ws, size_t ws_size,
                              hipStream_t stream) {
  const float* x = (const float*)d_in[0];
  const float* gam = (const float*)d_in[1];
  const float* bet = (const float*)d_in[2];
  const float* qkv_w = (const float*)d_in[3];
  const float* qkv_b = (const float*)d_in[4];
  const float* pr_w = (const float*)d_in[5];
  const float* pr_b = (const float*)d_in[6];
  float* out = (float*)d_out;

  gn_kernel<<<512, 256, 0, stream>>>(x, gam, bet);
  gemm_ct<0><<<dim3(4, 12, 16), 256, 0, stream>>>(qkv_w, qkv_b, nullptr, nullptr);
  attn_kernel<<<dim3(64, 8), 256, 0, stream>>>();
  gemm_ct<1><<<dim3(4, 4, 16), 256, 0, stream>>>(pr_w, pr_b, x, out);
}